// Round 4
// baseline (410.443 us; speedup 1.0000x reference)
//
#include <hip/hip_runtime.h>
#include <hip/hip_bf16.h>

typedef __attribute__((ext_vector_type(8))) short short8;
typedef __attribute__((ext_vector_type(4))) float f32x4;
typedef __attribute__((ext_vector_type(4))) unsigned int u32x4;

#define D_DIM 512
#define Q_DIM 128
#define M_BLK 256   // rows per block (8 waves: 4 row-groups x 2 col-groups)
#define RT 4        // 16-row tiles per wave (64 rows)
#define CT 4        // 16-col tiles per wave (64 cols)
#define KSTEP 32

// packed fp32x2 -> bf16x2 (RNE) via compiler-generated v_cvt_pk_bf16_f32
__device__ inline unsigned cvtpk2(float a, float b) {
    float2 t; t.x = a; t.y = b;
    __hip_bfloat162 h = __float22bfloat162_rn(t);
    unsigned u;
    __builtin_memcpy(&u, &h, 4);
    return u;
}

// scalar fp32 -> bf16 bits (RNE), used in prep only
__device__ inline unsigned short f2bf(float f) {
    union { float f; unsigned u; } v; v.f = f;
    unsigned r = v.u + 0x7fffu + ((v.u >> 16) & 1u);
    return (unsigned short)(r >> 16);
}

// One block per query: norms, threshold-tol, bf16-normalized query,
// out[q] = -1 init (reference's self-row exclusion; also makes the launch
// idempotent for graph replay since rank_kernel only atomicAdds).
__global__ __launch_bounds__(256) void prep_kernel(
    const float* __restrict__ qs, const float* __restrict__ ts,
    unsigned short* __restrict__ qn, float* __restrict__ thr_adj,
    int* __restrict__ out)
{
    __shared__ float red[3][4];
    const int qi  = blockIdx.x;
    const int tid = threadIdx.x;
    const float* qrow = qs + qi * D_DIM;
    const float* trow = ts + qi * D_DIM;
    float sq = 0.f, st = 0.f, sqt = 0.f;
    for (int d = tid; d < D_DIM; d += 256) {
        float a = qrow[d], b = trow[d];
        sq += a * a; st += b * b; sqt += a * b;
    }
    #pragma unroll
    for (int off = 32; off > 0; off >>= 1) {
        sq  += __shfl_down(sq, off);
        st  += __shfl_down(st, off);
        sqt += __shfl_down(sqt, off);
    }
    const int wave = tid >> 6, lane = tid & 63;
    if (lane == 0) { red[0][wave] = sq; red[1][wave] = st; red[2][wave] = sqt; }
    __syncthreads();
    sq  = red[0][0] + red[0][1] + red[0][2] + red[0][3];
    st  = red[1][0] + red[1][1] + red[1][2] + red[1][3];
    sqt = red[2][0] + red[2][1] + red[2][2] + red[2][3];
    const float qnorm  = fmaxf(sqrtf(sq), 1e-12f);
    const float tnorm  = fmaxf(sqrtf(st), 1e-12f);
    const float thresh = sqt / (qnorm * tnorm);
    if (tid == 0) {
        // mask = (s >= thr) | (|s - thr| <= atol + rtol*|thr|)  ==  s >= thr - tol
        thr_adj[qi] = thresh - (1e-8f + 1e-5f * fabsf(thresh));
        out[qi] = -1;
    }
    const float inv = 1.0f / qnorm;
    for (int d = tid; d < D_DIM; d += 256) {
        qn[qi * D_DIM + d] = f2bf(qrow[d] * inv);
    }
}

// sims = data(N x 512) @ qn^T(512 x 128), counted against thr_adj per column.
// Per block: 256 rows, 8 waves as 4 row-groups x 2 col-groups.
// Each wave: 64 rows x 64 cols -> acc[4][4] = 64 VGPRs (fits 4 waves/SIMD).
// A-frag (16x32 bf16): lane l holds A[l&15][(l>>4)*8 + 0..7] -> 2x float4 + cvt_pk.
// B-frag (32x16 bf16): lane l holds qn[col0 + (l&15)][k..k+7] (contig 16B).
// C/D: col = lane&15, row = (lane>>4)*4 + j   [guide §3, m89-verified]
__global__ __launch_bounds__(512, 4) void rank_kernel(
    const float* __restrict__ data,
    const unsigned short* __restrict__ qn,
    const float* __restrict__ thr_adj,
    int* __restrict__ out, int N)
{
    __shared__ int cnt_lds[Q_DIM];
    const int tid  = threadIdx.x;
    const int lane = tid & 63;
    const int wave = tid >> 6;
    const int wr   = wave >> 1;   // row-group 0..3
    const int wc   = wave & 1;    // col-group 0..1
    const int lr   = lane & 15;   // A row / B col within 16-tile
    const int kgrp = lane >> 4;   // 0..3
    const int koff = kgrp * 8;
    const int row0 = blockIdx.x * M_BLK + wr * 64;
    const int col0 = wc * 64;

    if (tid < Q_DIM) cnt_lds[tid] = 0;
    __syncthreads();

    f32x4 acc[RT][CT] = {};

    const float* aptr[RT];
    #pragma unroll
    for (int rt = 0; rt < RT; ++rt) {
        int r = row0 + rt * 16 + lr;
        if (r > N - 1) r = N - 1;   // clamp tail loads; masked at count
        aptr[rt] = data + (size_t)r * D_DIM + koff;
    }
    const unsigned short* bbase = qn + (size_t)(col0 + lr) * D_DIM + koff;

    #pragma unroll 2
    for (int k = 0; k < D_DIM; k += KSTEP) {
        short8 bfrag[CT];
        #pragma unroll
        for (int c = 0; c < CT; ++c)
            bfrag[c] = *(const short8*)(bbase + c * 16 * D_DIM + k);
        #pragma unroll
        for (int rt = 0; rt < RT; ++rt) {
            const float* p = aptr[rt] + k;
            float4 f0 = *(const float4*)(p);
            float4 f1 = *(const float4*)(p + 4);
            u32x4 pk;
            pk[0] = cvtpk2(f0.x, f0.y);
            pk[1] = cvtpk2(f0.z, f0.w);
            pk[2] = cvtpk2(f1.x, f1.y);
            pk[3] = cvtpk2(f1.z, f1.w);
            short8 afrag;
            __builtin_memcpy(&afrag, &pk, 16);
            #pragma unroll
            for (int c = 0; c < CT; ++c)
                acc[rt][c] = __builtin_amdgcn_mfma_f32_16x16x32_bf16(
                    afrag, bfrag[c], acc[rt][c], 0, 0, 0);
        }
    }

    // count sims >= thr per column, reduce across the wave's 4 k-groups
    const bool full = (row0 + 64 <= N);
    #pragma unroll
    for (int c = 0; c < CT; ++c) {
        const int col = col0 + c * 16 + lr;
        const float thr = thr_adj[col];
        int cnt = 0;
        if (full) {
            #pragma unroll
            for (int rt = 0; rt < RT; ++rt)
                #pragma unroll
                for (int j = 0; j < 4; ++j)
                    cnt += (acc[rt][c][j] >= thr) ? 1 : 0;
        } else {
            #pragma unroll
            for (int rt = 0; rt < RT; ++rt)
                #pragma unroll
                for (int j = 0; j < 4; ++j) {
                    int grow = row0 + rt * 16 + kgrp * 4 + j;
                    if (grow < N && acc[rt][c][j] >= thr) cnt++;
                }
        }
        cnt += __shfl_xor(cnt, 16);
        cnt += __shfl_xor(cnt, 32);
        if (lane < 16) atomicAdd(&cnt_lds[col], cnt);
    }
    __syncthreads();
    if (tid < Q_DIM) atomicAdd(&out[tid], cnt_lds[tid]);
}

extern "C" void kernel_launch(void* const* d_in, const int* in_sizes, int n_in,
                              void* d_out, int out_size, void* d_ws, size_t ws_size,
                              hipStream_t stream)
{
    const float* data    = (const float*)d_in[0];
    const float* queries = (const float*)d_in[1];
    const float* truths  = (const float*)d_in[2];
    const int N = in_sizes[0] / D_DIM;

    unsigned short* qn  = (unsigned short*)d_ws;
    float*          thr = (float*)((char*)d_ws + (size_t)Q_DIM * D_DIM * sizeof(unsigned short));
    int*            out = (int*)d_out;

    prep_kernel<<<Q_DIM, 256, 0, stream>>>(queries, truths, qn, thr, out);

    const int nblk = (N + M_BLK - 1) / M_BLK;
    rank_kernel<<<nblk, 512, 0, stream>>>(data, qn, thr, out, N);
}

// Round 5
// 282.876 us; speedup vs baseline: 1.4510x; 1.4510x over previous
//
#include <hip/hip_runtime.h>
#include <hip/hip_bf16.h>

typedef __attribute__((ext_vector_type(8))) short short8;
typedef __attribute__((ext_vector_type(4))) float f32x4;
typedef __attribute__((ext_vector_type(4))) unsigned int u32x4;

#define D_DIM 512
#define Q_DIM 128
#define M_BLK 256   // rows per block (4 waves x 64 rows)
#define RT 4        // 16-row tiles per wave (64 rows)
#define CT 8        // 16-col tiles (all 128 queries)
#define KSTEP 32

// packed fp32x2 -> bf16x2 (RNE) via compiler-generated v_cvt_pk_bf16_f32
__device__ inline unsigned cvtpk2(float a, float b) {
    float2 t; t.x = a; t.y = b;
    __hip_bfloat162 h = __float22bfloat162_rn(t);
    unsigned u;
    __builtin_memcpy(&u, &h, 4);
    return u;
}

// scalar fp32 -> bf16 bits (RNE), used in prep only
__device__ inline unsigned short f2bf(float f) {
    union { float f; unsigned u; } v; v.f = f;
    unsigned r = v.u + 0x7fffu + ((v.u >> 16) & 1u);
    return (unsigned short)(r >> 16);
}

// One block per query: norms, threshold-tol, bf16-normalized query,
// out[q] = -1 init (reference's self-row exclusion; also makes the launch
// idempotent for graph replay since rank_kernel only atomicAdds).
__global__ __launch_bounds__(256) void prep_kernel(
    const float* __restrict__ qs, const float* __restrict__ ts,
    unsigned short* __restrict__ qn, float* __restrict__ thr_adj,
    int* __restrict__ out)
{
    __shared__ float red[3][4];
    const int qi  = blockIdx.x;
    const int tid = threadIdx.x;
    const float* qrow = qs + qi * D_DIM;
    const float* trow = ts + qi * D_DIM;
    float sq = 0.f, st = 0.f, sqt = 0.f;
    for (int d = tid; d < D_DIM; d += 256) {
        float a = qrow[d], b = trow[d];
        sq += a * a; st += b * b; sqt += a * b;
    }
    #pragma unroll
    for (int off = 32; off > 0; off >>= 1) {
        sq  += __shfl_down(sq, off);
        st  += __shfl_down(st, off);
        sqt += __shfl_down(sqt, off);
    }
    const int wave = tid >> 6, lane = tid & 63;
    if (lane == 0) { red[0][wave] = sq; red[1][wave] = st; red[2][wave] = sqt; }
    __syncthreads();
    sq  = red[0][0] + red[0][1] + red[0][2] + red[0][3];
    st  = red[1][0] + red[1][1] + red[1][2] + red[1][3];
    sqt = red[2][0] + red[2][1] + red[2][2] + red[2][3];
    const float qnorm  = fmaxf(sqrtf(sq), 1e-12f);
    const float tnorm  = fmaxf(sqrtf(st), 1e-12f);
    const float thresh = sqt / (qnorm * tnorm);
    if (tid == 0) {
        // mask = (s >= thr) | (|s - thr| <= atol + rtol*|thr|)  ==  s >= thr - tol
        thr_adj[qi] = thresh - (1e-8f + 1e-5f * fabsf(thresh));
        out[qi] = -1;
    }
    const float inv = 1.0f / qnorm;
    for (int d = tid; d < D_DIM; d += 256) {
        qn[qi * D_DIM + d] = f2bf(qrow[d] * inv);
    }
}

// sims = data(N x 512) @ qn^T(512 x 128), counted against thr_adj per column.
// Per block: 256 rows, 4 waves, each wave owns 64 rows x all 128 cols.
// Software-pipelined: cvt current A -> issue next A loads (WAR-ordered after
// the cvt) -> B loads -> MFMA block, so A's HBM latency hides under MFMA.
// A-frag (16x32 bf16): lane l holds A[l&15][(l>>4)*8 + 0..7].
// B-frag (32x16 bf16): lane l holds qn[l&15][k..k+7] (contig 16B).
// C/D: col = lane&15, row = (lane>>4)*4 + j   [guide §3, m89-verified]
__global__ __launch_bounds__(256, 2) void rank_kernel(
    const float* __restrict__ data,
    const unsigned short* __restrict__ qn,
    const float* __restrict__ thr_adj,
    int* __restrict__ out, int N)
{
    __shared__ int cnt_lds[Q_DIM];
    const int tid  = threadIdx.x;
    const int lane = tid & 63;
    const int wave = tid >> 6;
    const int lr   = lane & 15;   // A row / B col within 16-tile
    const int kgrp = lane >> 4;   // 0..3
    const int koff = kgrp * 8;
    const int row0 = blockIdx.x * M_BLK + wave * 64;

    for (int i = tid; i < Q_DIM; i += 256) cnt_lds[i] = 0;
    __syncthreads();

    f32x4 acc[RT][CT] = {};

    const float* aptr[RT];
    #pragma unroll
    for (int rt = 0; rt < RT; ++rt) {
        int r = row0 + rt * 16 + lr;
        if (r > N - 1) r = N - 1;   // clamp tail loads; masked at count
        aptr[rt] = data + (size_t)r * D_DIM + koff;
    }
    const unsigned short* bbase = qn + lr * D_DIM + koff;

    // prologue: issue first A tile's loads
    float4 c0[RT], c1[RT];
    #pragma unroll
    for (int rt = 0; rt < RT; ++rt) {
        c0[rt] = *(const float4*)(aptr[rt]);
        c1[rt] = *(const float4*)(aptr[rt] + 4);
    }

    #pragma unroll 1
    for (int k = 0; k < D_DIM; k += KSTEP) {
        // 1. convert current A tile (frees c0/c1 for the prefetch)
        short8 afrag[RT];
        #pragma unroll
        for (int rt = 0; rt < RT; ++rt) {
            u32x4 pk;
            pk[0] = cvtpk2(c0[rt].x, c0[rt].y);
            pk[1] = cvtpk2(c0[rt].z, c0[rt].w);
            pk[2] = cvtpk2(c1[rt].x, c1[rt].y);
            pk[3] = cvtpk2(c1[rt].z, c1[rt].w);
            __builtin_memcpy(&afrag[rt], &pk, 16);
        }
        // 2. prefetch next K-step's A tile (flies during B loads + MFMAs)
        if (k + KSTEP < D_DIM) {
            #pragma unroll
            for (int rt = 0; rt < RT; ++rt) {
                c0[rt] = *(const float4*)(aptr[rt] + k + KSTEP);
                c1[rt] = *(const float4*)(aptr[rt] + k + KSTEP + 4);
            }
        }
        // 3. B fragments (L2-resident), 4. MFMA block (c-outer: bfrag[c]
        //    latencies hide under preceding c-groups' MFMAs)
        short8 bfrag[CT];
        #pragma unroll
        for (int c = 0; c < CT; ++c)
            bfrag[c] = *(const short8*)(bbase + c * 16 * D_DIM + k);
        #pragma unroll
        for (int c = 0; c < CT; ++c)
            #pragma unroll
            for (int rt = 0; rt < RT; ++rt)
                acc[rt][c] = __builtin_amdgcn_mfma_f32_16x16x32_bf16(
                    afrag[rt], bfrag[c], acc[rt][c], 0, 0, 0);
    }

    // count sims >= thr per column, reduce across the wave's 4 k-groups
    const bool full = (row0 + 64 <= N);
    #pragma unroll
    for (int c = 0; c < CT; ++c) {
        const float thr = thr_adj[c * 16 + lr];
        int cnt = 0;
        if (full) {
            #pragma unroll
            for (int rt = 0; rt < RT; ++rt)
                #pragma unroll
                for (int j = 0; j < 4; ++j)
                    cnt += (acc[rt][c][j] >= thr) ? 1 : 0;
        } else {
            #pragma unroll
            for (int rt = 0; rt < RT; ++rt)
                #pragma unroll
                for (int j = 0; j < 4; ++j) {
                    int grow = row0 + rt * 16 + kgrp * 4 + j;
                    if (grow < N && acc[rt][c][j] >= thr) cnt++;
                }
        }
        cnt += __shfl_xor(cnt, 16);
        cnt += __shfl_xor(cnt, 32);
        if (lane < 16) atomicAdd(&cnt_lds[c * 16 + lr], cnt);
    }
    __syncthreads();
    for (int i = tid; i < Q_DIM; i += 256) {
        atomicAdd(&out[i], cnt_lds[i]);
    }
}

extern "C" void kernel_launch(void* const* d_in, const int* in_sizes, int n_in,
                              void* d_out, int out_size, void* d_ws, size_t ws_size,
                              hipStream_t stream)
{
    const float* data    = (const float*)d_in[0];
    const float* queries = (const float*)d_in[1];
    const float* truths  = (const float*)d_in[2];
    const int N = in_sizes[0] / D_DIM;

    unsigned short* qn  = (unsigned short*)d_ws;
    float*          thr = (float*)((char*)d_ws + (size_t)Q_DIM * D_DIM * sizeof(unsigned short));
    int*            out = (int*)d_out;

    prep_kernel<<<Q_DIM, 256, 0, stream>>>(queries, truths, qn, thr, out);

    const int nblk = (N + M_BLK - 1) / M_BLK;
    rank_kernel<<<nblk, 256, 0, stream>>>(data, qn, thr, out, N);
}

// Round 6
// 230.387 us; speedup vs baseline: 1.7815x; 1.2278x over previous
//
#include <hip/hip_runtime.h>
#include <hip/hip_bf16.h>

typedef __attribute__((ext_vector_type(8))) short short8;
typedef __attribute__((ext_vector_type(4))) float f32x4;
typedef __attribute__((ext_vector_type(4))) unsigned int u32x4;

#define D_DIM 512
#define Q_DIM 128
#define M_BLK 256   // rows per block (4 waves x 64 rows)
#define RT 4        // 16-row tiles per wave (64 rows)
#define CT 8        // 16-col tiles (all 128 queries)
#define KSTEP 32

// packed fp32x2 -> bf16x2 (RNE) via compiler-generated v_cvt_pk_bf16_f32
__device__ inline unsigned cvtpk2(float a, float b) {
    float2 t; t.x = a; t.y = b;
    __hip_bfloat162 h = __float22bfloat162_rn(t);
    unsigned u;
    __builtin_memcpy(&u, &h, 4);
    return u;
}

// scalar fp32 -> bf16 bits (RNE), used in prep only
__device__ inline unsigned short f2bf(float f) {
    union { float f; unsigned u; } v; v.f = f;
    unsigned r = v.u + 0x7fffu + ((v.u >> 16) & 1u);
    return (unsigned short)(r >> 16);
}

// One block per query qi: norms, threshold-tol, bf16-normalized query written
// in FRAGMENT-PACKED layout, out[qi] = -1 init (self-row exclusion; also makes
// the launch idempotent for graph replay since rank_kernel only atomicAdds).
//
// Packed layout: B_p[((kblk*8 + c)*64 + kgrp*16 + lr)*8 + j]
//   = qn[c*16 + lr][kblk*32 + kgrp*8 + j]
// so rank_kernel's bfrag load is lane-contiguous 16B (1KB/wave-instr).
__global__ __launch_bounds__(256) void prep_kernel(
    const float* __restrict__ qs, const float* __restrict__ ts,
    unsigned short* __restrict__ qn_p, float* __restrict__ thr_adj,
    int* __restrict__ out)
{
    __shared__ float red[3][4];
    const int qi  = blockIdx.x;
    const int tid = threadIdx.x;
    const float* qrow = qs + qi * D_DIM;
    const float* trow = ts + qi * D_DIM;
    float sq = 0.f, st = 0.f, sqt = 0.f;
    for (int d = tid; d < D_DIM; d += 256) {
        float a = qrow[d], b = trow[d];
        sq += a * a; st += b * b; sqt += a * b;
    }
    #pragma unroll
    for (int off = 32; off > 0; off >>= 1) {
        sq  += __shfl_down(sq, off);
        st  += __shfl_down(st, off);
        sqt += __shfl_down(sqt, off);
    }
    const int wave = tid >> 6, lane = tid & 63;
    if (lane == 0) { red[0][wave] = sq; red[1][wave] = st; red[2][wave] = sqt; }
    __syncthreads();
    sq  = red[0][0] + red[0][1] + red[0][2] + red[0][3];
    st  = red[1][0] + red[1][1] + red[1][2] + red[1][3];
    sqt = red[2][0] + red[2][1] + red[2][2] + red[2][3];
    const float qnorm  = fmaxf(sqrtf(sq), 1e-12f);
    const float tnorm  = fmaxf(sqrtf(st), 1e-12f);
    const float thresh = sqt / (qnorm * tnorm);
    if (tid == 0) {
        // mask = (s >= thr) | (|s - thr| <= atol + rtol*|thr|)  ==  s >= thr - tol
        thr_adj[qi] = thresh - (1e-8f + 1e-5f * fabsf(thresh));
        out[qi] = -1;
    }
    const float inv = 1.0f / qnorm;
    const int c  = qi >> 4;      // 16-col tile index
    const int lr = qi & 15;      // col within tile
    for (int d = tid; d < D_DIM; d += 256) {
        const int kblk = d >> 5;         // which 32-K step
        const int rem  = d & 31;
        const int kgrp = rem >> 3;       // 0..3
        const int j    = rem & 7;
        const size_t off = ((size_t)((kblk << 3) + c) * 64 + (kgrp << 4) + lr) * 8 + j;
        qn_p[off] = f2bf(qrow[d] * inv);
    }
}

// sims = data(N x 512) @ qn^T(512 x 128), counted against thr_adj per column.
// Per block: 256 rows, 4 waves, each wave owns 64 rows x all 128 cols.
// Software-pipelined A (cvt current -> prefetch next -> B loads -> MFMAs).
// A-frag (16x32 bf16): lane l holds A[l&15][(l>>4)*8 + 0..7].
// B-frag: packed layout, lane-contiguous 16B per (kblk, c).
// C/D: col = lane&15, row = (lane>>4)*4 + j   [guide §3, m89-verified]
__global__ __launch_bounds__(256, 2) void rank_kernel(
    const float* __restrict__ data,
    const unsigned short* __restrict__ qn_p,
    const float* __restrict__ thr_adj,
    int* __restrict__ out, int N)
{
    __shared__ int cnt_lds[Q_DIM];
    const int tid  = threadIdx.x;
    const int lane = tid & 63;
    const int wave = tid >> 6;
    const int lr   = lane & 15;   // A row / B col within 16-tile
    const int kgrp = lane >> 4;   // 0..3
    const int koff = kgrp * 8;
    const int row0 = blockIdx.x * M_BLK + wave * 64;

    for (int i = tid; i < Q_DIM; i += 256) cnt_lds[i] = 0;
    __syncthreads();

    f32x4 acc[RT][CT] = {};

    const float* aptr[RT];
    #pragma unroll
    for (int rt = 0; rt < RT; ++rt) {
        int r = row0 + rt * 16 + lr;
        if (r > N - 1) r = N - 1;   // clamp tail loads; masked at count
        aptr[rt] = data + (size_t)r * D_DIM + koff;
    }
    // per-lane base into the packed B: + lane*8 shorts (16B)
    const unsigned short* bbase = qn_p + (size_t)lane * 8;

    // prologue: issue first A tile's loads
    float4 c0[RT], c1[RT];
    #pragma unroll
    for (int rt = 0; rt < RT; ++rt) {
        c0[rt] = *(const float4*)(aptr[rt]);
        c1[rt] = *(const float4*)(aptr[rt] + 4);
    }

    #pragma unroll 1
    for (int k = 0; k < D_DIM; k += KSTEP) {
        const int kblk = k >> 5;
        // 1. convert current A tile (frees c0/c1 for the prefetch)
        short8 afrag[RT];
        #pragma unroll
        for (int rt = 0; rt < RT; ++rt) {
            u32x4 pk;
            pk[0] = cvtpk2(c0[rt].x, c0[rt].y);
            pk[1] = cvtpk2(c0[rt].z, c0[rt].w);
            pk[2] = cvtpk2(c1[rt].x, c1[rt].y);
            pk[3] = cvtpk2(c1[rt].z, c1[rt].w);
            __builtin_memcpy(&afrag[rt], &pk, 16);
        }
        // 2. prefetch next K-step's A tile (flies during B loads + MFMAs)
        if (k + KSTEP < D_DIM) {
            #pragma unroll
            for (int rt = 0; rt < RT; ++rt) {
                c0[rt] = *(const float4*)(aptr[rt] + k + KSTEP);
                c1[rt] = *(const float4*)(aptr[rt] + k + KSTEP + 4);
            }
        }
        // 3. B fragments — packed, lane-contiguous 16B (1KB per wave instr)
        short8 bfrag[CT];
        #pragma unroll
        for (int c = 0; c < CT; ++c)
            bfrag[c] = *(const short8*)(bbase + (size_t)((kblk << 3) + c) * 512);
        // 4. MFMA block (c-outer: bfrag latencies hide under preceding MFMAs)
        #pragma unroll
        for (int c = 0; c < CT; ++c)
            #pragma unroll
            for (int rt = 0; rt < RT; ++rt)
                acc[rt][c] = __builtin_amdgcn_mfma_f32_16x16x32_bf16(
                    afrag[rt], bfrag[c], acc[rt][c], 0, 0, 0);
    }

    // count sims >= thr per column, reduce across the wave's 4 k-groups
    const bool full = (row0 + 64 <= N);
    #pragma unroll
    for (int c = 0; c < CT; ++c) {
        const float thr = thr_adj[c * 16 + lr];
        int cnt = 0;
        if (full) {
            #pragma unroll
            for (int rt = 0; rt < RT; ++rt)
                #pragma unroll
                for (int j = 0; j < 4; ++j)
                    cnt += (acc[rt][c][j] >= thr) ? 1 : 0;
        } else {
            #pragma unroll
            for (int rt = 0; rt < RT; ++rt)
                #pragma unroll
                for (int j = 0; j < 4; ++j) {
                    int grow = row0 + rt * 16 + kgrp * 4 + j;
                    if (grow < N && acc[rt][c][j] >= thr) cnt++;
                }
        }
        cnt += __shfl_xor(cnt, 16);
        cnt += __shfl_xor(cnt, 32);
        if (lane < 16) atomicAdd(&cnt_lds[c * 16 + lr], cnt);
    }
    __syncthreads();
    for (int i = tid; i < Q_DIM; i += 256) {
        atomicAdd(&out[i], cnt_lds[i]);
    }
}

extern "C" void kernel_launch(void* const* d_in, const int* in_sizes, int n_in,
                              void* d_out, int out_size, void* d_ws, size_t ws_size,
                              hipStream_t stream)
{
    const float* data    = (const float*)d_in[0];
    const float* queries = (const float*)d_in[1];
    const float* truths  = (const float*)d_in[2];
    const int N = in_sizes[0] / D_DIM;

    unsigned short* qn_p = (unsigned short*)d_ws;
    float*          thr  = (float*)((char*)d_ws + (size_t)Q_DIM * D_DIM * sizeof(unsigned short));
    int*            out  = (int*)d_out;

    prep_kernel<<<Q_DIM, 256, 0, stream>>>(queries, truths, qn_p, thr, out);

    const int nblk = (N + M_BLK - 1) / M_BLK;
    rank_kernel<<<nblk, 256, 0, stream>>>(data, qn_p, thr, out, N);
}